// Round 9
// baseline (530.579 us; speedup 1.0000x reference)
//
#include <hip/hip_runtime.h>
#include <hip/hip_bf16.h>
#include <math.h>

// MOE: out[b,o] = sum_n gelu(x@gw^T+gb)[b,n] * (x @ W_n^T)[b,o]
// R9: xs pre-scale -> pure bf16 GEMM. MFMA-dominant geometry: BM=BN=256,
// BK=64, 4 waves (2x2) each owning 128x128 via 4x4 blocks of
// mfma_f32_32x32x16_bf16 (acc 256 regs, 1 wave/SIMD). Simple 2-phase loop
// (stage-next / interior / syncthreads) — serial floor is now MFMA (2483 cyc)
// not LDS (reads 128KB ~1400 cyc). LDS [256][128B] rows, granule^=(row&7)
// both-sides swizzle. Split-K x4 via fp32 atomics into zeroed out.

#define BSZ  4096
#define NEXP 32
#define IDIM 1024
#define ODIM 1024

typedef unsigned short u16;
typedef __attribute__((ext_vector_type(8))) short bf16x8;
typedef __attribute__((ext_vector_type(16))) float f32x16;

#define GLOAD_LDS16(g, l) __builtin_amdgcn_global_load_lds( \
    (const __attribute__((address_space(1))) void*)(g),     \
    (__attribute__((address_space(3))) void*)(l), 16, 0, 0)

#define SBAR __builtin_amdgcn_sched_barrier(0)

__device__ __forceinline__ u16 f2bf(float f) {
  unsigned u = __float_as_uint(f);
  return (u16)((u + 0x7FFFu + ((u >> 16) & 1u)) >> 16);  // RNE
}

// ---------------- zero d_out ----------------
__global__ void zero_kernel(float* __restrict__ out) {
  int i = blockIdx.x * blockDim.x + threadIdx.x;
  ((float4*)out)[i] = make_float4(0.f, 0.f, 0.f, 0.f);
}

// ---------------- fp32 -> bf16 conversion (8 elems/thread) ----------------
__global__ void conv_kernel(const float* __restrict__ in, u16* __restrict__ outb) {
  int i = blockIdx.x * blockDim.x + threadIdx.x;
  const float4* p = (const float4*)in + (size_t)i * 2;
  float4 a = p[0], b = p[1];
  union { bf16x8 v; u16 s[8]; } o;
  o.s[0] = f2bf(a.x); o.s[1] = f2bf(a.y); o.s[2] = f2bf(a.z); o.s[3] = f2bf(a.w);
  o.s[4] = f2bf(b.x); o.s[5] = f2bf(b.y); o.s[6] = f2bf(b.z); o.s[7] = f2bf(b.w);
  ((bf16x8*)outb)[i] = o.v;
}

// ---------------- gate: gT[n][b] = gelu(x[b]·gw[n] + gb[n]) ----------------
__global__ void gate_kernel(const float* __restrict__ x, const float* __restrict__ gw,
                            const float* __restrict__ gb, float* __restrict__ gT) {
  const int lane = threadIdx.x & 63;
  const int row = blockIdx.x * 4 + (threadIdx.x >> 6);
  const float4* xr = (const float4*)(x + (size_t)row * IDIM);
  float4 xv[4];
#pragma unroll
  for (int t = 0; t < 4; ++t) xv[t] = xr[t * 64 + lane];
  for (int n = 0; n < NEXP; ++n) {
    const float4* wr = (const float4*)(gw + (size_t)n * IDIM);
    float s = 0.f;
#pragma unroll
    for (int t = 0; t < 4; ++t) {
      float4 wv = wr[t * 64 + lane];
      s += xv[t].x * wv.x + xv[t].y * wv.y + xv[t].z * wv.z + xv[t].w * wv.w;
    }
#pragma unroll
    for (int off = 32; off > 0; off >>= 1) s += __shfl_down(s, off, 64);
    if (lane == 0) {
      float v = s + gb[n];
      gT[(size_t)n * BSZ + row] = 0.5f * v * (1.0f + erff(v * 0.70710678118f));
    }
  }
}

// ---------------- xs[e][b][i] = bf16(g[b, base+e] * x[b][i]) ----------------
__global__ void scale_kernel(const float* __restrict__ x, const float* __restrict__ gT,
                             u16* __restrict__ xs, int base) {
  int idx = blockIdx.x * 256 + threadIdx.x;
  int chunk = idx & 127;
  int b = (idx >> 7) & 4095;
  int e = idx >> 19;
  const float4* xp = (const float4*)(x + ((size_t)b << 10) + chunk * 8);
  float4 v0 = xp[0], v1 = xp[1];
  float g = gT[((size_t)(base + e) << 12) + b];
  union { bf16x8 v; u16 s[8]; } o;
  o.s[0] = f2bf(g * v0.x); o.s[1] = f2bf(g * v0.y);
  o.s[2] = f2bf(g * v0.z); o.s[3] = f2bf(g * v0.w);
  o.s[4] = f2bf(g * v1.x); o.s[5] = f2bf(g * v1.y);
  o.s[6] = f2bf(g * v1.z); o.s[7] = f2bf(g * v1.w);
  *(bf16x8*)&xs[((size_t)e << 22) + ((size_t)b << 10) + chunk * 8] = o.v;
}

// ---------------- main GEMM ----------------
// 256 blocks (1/CU exact), 256 threads (4 waves 2x2, wave = 128x128 output).
// Block tile 256x256, BK=64. Wave: 4x4 grid of 32x32 accumulator blocks.
__global__ __launch_bounds__(256, 1) void gemm_kernel(
    const u16* __restrict__ xs,   // [EPR][4096][1024] bf16 (pre-scaled)
    const u16* __restrict__ wb,   // [EPR][1024][1024] bf16 (e,o,i)
    float* __restrict__ out,      // [4096][1024] fp32
    int eps)                      // experts per split (EPR/4)
{
  __shared__ u16 As[2][256 * 64];   // 2 x 32 KB
  __shared__ u16 Bs[2][256 * 64];   // 2 x 32 KB (128 KiB total)

  const int tid  = threadIdx.x;
  const int lane = tid & 63;
  const int wid  = tid >> 6;     // 0..3
  const int wm   = wid >> 1;     // 0..1 (M half)
  const int wn   = wid & 1;      // 0..1 (N half)

  // XCD-chunked swizzle (256 % 8 == 0 -> bijective); 16 blocks/grp share W panel
  const int orig  = blockIdx.x;
  const int wgid  = (orig & 7) * 32 + (orig >> 3);
  const int mtile = wgid & 15;
  const int grp   = wgid >> 4;          // 0..15 = (ntile, split)
  const int split = grp & 3;
  const int col0  = (grp >> 2) * 256;
  const int row0  = mtile * 256;

  // staging: call l, wave wid -> tile rows (l*4+wid)*8 + (lane>>3), granule lane&7
  // pre-swizzled source granule jsrc = (lane&7) ^ (row&7), row&7 = lane>>3
  const int jsrc = (lane & 7) ^ (lane >> 3);
  size_t a_off[8], b_off[8];
#pragma unroll
  for (int l = 0; l < 8; ++l) {
    const int tr = (l * 4 + wid) * 8 + (lane >> 3);
    a_off[l] = ((size_t)(row0 + tr) << 10) + jsrc * 8;
    b_off[l] = ((size_t)(col0 + tr) << 10) + jsrc * 8;
  }

  // fragment addressing (32x32x16): op row = lane&31, k = (lane>>5)*8 + j
  const int r31 = lane & 31;
  const int hk  = lane >> 5;      // 0..1
  const int l7  = lane & 7;
  int arow[4], brow[4], pg[4];
#pragma unroll
  for (int rb = 0; rb < 4; ++rb) arow[rb] = (wm * 128 + rb * 32 + r31) * 64;
#pragma unroll
  for (int cb = 0; cb < 4; ++cb) brow[cb] = (wn * 128 + cb * 32 + r31) * 64;
#pragma unroll
  for (int ks = 0; ks < 4; ++ks) pg[ks] = ((ks * 2 + hk) ^ l7) * 8;

  f32x16 acc[4][4];
#pragma unroll
  for (int i = 0; i < 4; ++i)
#pragma unroll
    for (int j = 0; j < 4; ++j)
#pragma unroll
      for (int q = 0; q < 16; ++q) acc[i][j][q] = 0.f;

  auto STAGE = [&](int buf, int kt) {
    const int e = split * eps + (kt >> 4);
    const size_t i0 = (size_t)((kt & 15) << 6);
#pragma unroll
    for (int l = 0; l < 8; ++l)
      GLOAD_LDS16(xs + ((size_t)e << 22) + a_off[l] + i0, &As[buf][(l * 4 + wid) * 512]);
#pragma unroll
    for (int l = 0; l < 8; ++l)
      GLOAD_LDS16(wb + ((size_t)e << 20) + b_off[l] + i0, &Bs[buf][(l * 4 + wid) * 512]);
  };

  const int NKT = eps << 4;   // 16 kt per expert (BK=64)

  STAGE(0, 0);
  __syncthreads();   // tile 0 resident everywhere

  int cur = 0;
#pragma unroll 1
  for (int kt = 0; kt < NKT; ++kt) {
    if (kt + 1 < NKT) STAGE(cur ^ 1, kt + 1);
    SBAR;   // keep prefetch issue ahead of the interior

    const u16* A_ = &As[cur][0];
    const u16* B_ = &Bs[cur][0];

#pragma unroll
    for (int ks = 0; ks < 4; ++ks) {
      bf16x8 a[4], b[4];
#pragma unroll
      for (int rb = 0; rb < 4; ++rb) a[rb] = *(const bf16x8*)&A_[arow[rb] + pg[ks]];
#pragma unroll
      for (int cb = 0; cb < 4; ++cb) b[cb] = *(const bf16x8*)&B_[brow[cb] + pg[ks]];
#pragma unroll
      for (int rb = 0; rb < 4; ++rb)
#pragma unroll
        for (int cb = 0; cb < 4; ++cb)
          acc[rb][cb] = __builtin_amdgcn_mfma_f32_32x32x16_bf16(
              a[rb], b[cb], acc[rb][cb], 0, 0, 0);
    }

    __syncthreads();   // drains vmcnt+lgkm; ~2600-cyc body covers HBM latency
    cur ^= 1;
  }

  // split-K contribution via atomics (out pre-zeroed)
  // C/D layout (32x32): col = lane&31, row = (q&3) + 8*(q>>2) + 4*(lane>>5)
#pragma unroll
  for (int rb = 0; rb < 4; ++rb)
#pragma unroll
    for (int cb = 0; cb < 4; ++cb) {
      const int rbase = row0 + wm * 128 + rb * 32 + hk * 4;
      const int c     = col0 + wn * 128 + cb * 32 + r31;
#pragma unroll
      for (int q = 0; q < 16; ++q) {
        const int r = rbase + (q & 3) + 8 * (q >> 2);
        atomicAdd(out + (size_t)r * ODIM + c, acc[rb][cb][q]);
      }
    }
}

extern "C" void kernel_launch(void* const* d_in, const int* in_sizes, int n_in,
                              void* d_out, int out_size, void* d_ws, size_t ws_size,
                              hipStream_t stream) {
  const float* x  = (const float*)d_in[0];   // [4096][1024]
  const float* w  = (const float*)d_in[1];   // [32][1024][1024]
  const float* gw = (const float*)d_in[2];   // [32][1024]
  const float* gb = (const float*)d_in[3];   // [32]
  float* out = (float*)d_out;                // [4096][1024]

  const size_t MiB = 1u << 20;
  int EPR;
  if      (ws_size >= 321 * MiB) EPR = 32;
  else if (ws_size >=  81 * MiB) EPR = 8;
  else                           EPR = 4;
  const int NR = NEXP / EPR;

  u16*   xs   = (u16*)d_ws;                                     // EPR * 8 MiB
  u16*   wbuf = (u16*)((char*)d_ws + (size_t)EPR * 8 * MiB);    // EPR * 2 MiB
  float* gT   = (float*)((char*)d_ws + (size_t)EPR * 10 * MiB); // 512 KiB

  zero_kernel<<<(BSZ * ODIM / 4) / 256, 256, 0, stream>>>(out);
  gate_kernel<<<BSZ / 4, 256, 0, stream>>>(x, gw, gb, gT);

  for (int r = 0; r < NR; ++r) {
    conv_kernel<<<EPR * 512, 256, 0, stream>>>(w + (size_t)r * EPR * IDIM * ODIM, wbuf);
    scale_kernel<<<EPR * 2048, 256, 0, stream>>>(x, gT, xs, r * EPR);
    gemm_kernel<<<256, 256, 0, stream>>>(xs, wbuf, out, EPR / 4);
  }
}

// Round 10
// 478.622 us; speedup vs baseline: 1.1086x; 1.1086x over previous
//
#include <hip/hip_runtime.h>
#include <hip/hip_bf16.h>
#include <math.h>

// MOE: out[b,o] = sum_n gelu(x@gw^T+gb)[b,n] * (x @ W_n^T)[b,o]
// R10: xs pre-scale -> pure bf16 GEMM. R8 geometry (proven 2-block/CU overlap
// mechanism) + R4's proven counted-wait pattern: BM=256 BN=128 BK=32, 4 waves
// (2Mx2N, wave 128x64), TRI-buffered LDS (72KB -> 2 blocks/CU), stage(kt+2)
// at kt-top, vmcnt(6) + raw s_barrier once per kt (never drain-0 in loop).
// Interior (12 ds_read + 32 MFMA) compiler-scheduled. Split-K x4 atomics.

#define BSZ  4096
#define NEXP 32
#define IDIM 1024
#define ODIM 1024

typedef unsigned short u16;
typedef __attribute__((ext_vector_type(8))) short bf16x8;
typedef __attribute__((ext_vector_type(4))) float f32x4;

#define GLOAD_LDS16(g, l) __builtin_amdgcn_global_load_lds( \
    (const __attribute__((address_space(1))) void*)(g),     \
    (__attribute__((address_space(3))) void*)(l), 16, 0, 0)

#define SBAR __builtin_amdgcn_sched_barrier(0)
#define WAITV6 do { asm volatile("s_waitcnt vmcnt(6)" ::: "memory"); SBAR; } while (0)
#define WAITV0 do { asm volatile("s_waitcnt vmcnt(0)" ::: "memory"); SBAR; } while (0)
#define BARRIER do { SBAR; __builtin_amdgcn_s_barrier(); SBAR; } while (0)

__device__ __forceinline__ u16 f2bf(float f) {
  unsigned u = __float_as_uint(f);
  return (u16)((u + 0x7FFFu + ((u >> 16) & 1u)) >> 16);  // RNE
}

// ---------------- zero d_out ----------------
__global__ void zero_kernel(float* __restrict__ out) {
  int i = blockIdx.x * blockDim.x + threadIdx.x;
  ((float4*)out)[i] = make_float4(0.f, 0.f, 0.f, 0.f);
}

// ---------------- fp32 -> bf16 conversion (8 elems/thread) ----------------
__global__ void conv_kernel(const float* __restrict__ in, u16* __restrict__ outb) {
  int i = blockIdx.x * blockDim.x + threadIdx.x;
  const float4* p = (const float4*)in + (size_t)i * 2;
  float4 a = p[0], b = p[1];
  union { bf16x8 v; u16 s[8]; } o;
  o.s[0] = f2bf(a.x); o.s[1] = f2bf(a.y); o.s[2] = f2bf(a.z); o.s[3] = f2bf(a.w);
  o.s[4] = f2bf(b.x); o.s[5] = f2bf(b.y); o.s[6] = f2bf(b.z); o.s[7] = f2bf(b.w);
  ((bf16x8*)outb)[i] = o.v;
}

// ---------------- gate: gT[n][b] = gelu(x[b]·gw[n] + gb[n]) ----------------
__global__ void gate_kernel(const float* __restrict__ x, const float* __restrict__ gw,
                            const float* __restrict__ gb, float* __restrict__ gT) {
  const int lane = threadIdx.x & 63;
  const int row = blockIdx.x * 4 + (threadIdx.x >> 6);
  const float4* xr = (const float4*)(x + (size_t)row * IDIM);
  float4 xv[4];
#pragma unroll
  for (int t = 0; t < 4; ++t) xv[t] = xr[t * 64 + lane];
  for (int n = 0; n < NEXP; ++n) {
    const float4* wr = (const float4*)(gw + (size_t)n * IDIM);
    float s = 0.f;
#pragma unroll
    for (int t = 0; t < 4; ++t) {
      float4 wv = wr[t * 64 + lane];
      s += xv[t].x * wv.x + xv[t].y * wv.y + xv[t].z * wv.z + xv[t].w * wv.w;
    }
#pragma unroll
    for (int off = 32; off > 0; off >>= 1) s += __shfl_down(s, off, 64);
    if (lane == 0) {
      float v = s + gb[n];
      gT[(size_t)n * BSZ + row] = 0.5f * v * (1.0f + erff(v * 0.70710678118f));
    }
  }
}

// ---------------- xs[e][b][i] = bf16(g[b, base+e] * xb[b][i]) ----------------
__global__ void scale_kernel(const u16* __restrict__ xb, const float* __restrict__ gT,
                             u16* __restrict__ xs, int base) {
  int idx = blockIdx.x * 256 + threadIdx.x;
  int chunk = idx & 127;
  int b = (idx >> 7) & 4095;
  int e = idx >> 19;
  union { bf16x8 v; u16 s[8]; } iv, o;
  iv.v = *(const bf16x8*)&xb[((size_t)b << 10) + chunk * 8];
  float g = gT[((size_t)(base + e) << 12) + b];
#pragma unroll
  for (int j = 0; j < 8; ++j) {
    float f = __uint_as_float((unsigned)iv.s[j] << 16);
    o.s[j] = f2bf(g * f);
  }
  *(bf16x8*)&xs[((size_t)e << 22) + ((size_t)b << 10) + chunk * 8] = o.v;
}

// ---------------- main GEMM ----------------
// 512 blocks (2/CU), 256 threads (4 waves 2Mx2N, wave = 128x64 output).
// Block tile 256x128, BK=32. NKT = eps*32. Tri-buffered LDS, distance-2
// prefetch, vmcnt(6)+s_barrier once per kt.
__global__ __launch_bounds__(256, 2) void gemm_kernel(
    const u16* __restrict__ xs,   // [EPR][4096][1024] bf16 (pre-scaled)
    const u16* __restrict__ wb,   // [EPR][1024][1024] bf16 (e,o,i)
    float* __restrict__ out,      // [4096][1024] fp32
    int eps)                      // experts per split (EPR/4)
{
  __shared__ u16 As[3][256 * 32];   // 3 x 16 KB
  __shared__ u16 Bs[3][128 * 32];   // 3 x  8 KB  (72 KB -> 2 blocks/CU)

  const int tid  = threadIdx.x;
  const int lane = tid & 63;
  const int wid  = tid >> 6;     // 0..3
  const int wm   = wid >> 1;     // 0..1 (M)
  const int wn   = wid & 1;      // 0..1 (N)

  // XCD-chunked swizzle (512 % 8 == 0 -> bijective); mtile innermost: the 64
  // blocks of one XCD-chunk = 16 mtiles x 4 grps (mostly same split) -> A-slice
  // shared by same-XCD ntile-blocks, W panel shared by 16 mtile-blocks.
  const int orig  = blockIdx.x;
  const int wgid  = (orig & 7) * 64 + (orig >> 3);
  const int mtile = wgid & 15;
  const int grp   = wgid >> 4;          // 0..31
  const int split = grp >> 3;           // 0..3
  const int ntile = grp & 7;            // 0..7
  const int row0  = mtile * 256;
  const int col0  = ntile * 128;

  // staging: per call (l, wid): row r = (l*4+wid)*16 + (lane>>2),
  // LDS slot js = lane&3, pre-swizzled source granule = js ^ ((r>>1)&3)
  const int rsub = lane >> 2;    // 0..15
  const int js   = lane & 3;

  const int frow = lane & 15;
  const int hi   = lane >> 4;

  f32x4 acc[8][4];
#pragma unroll
  for (int i = 0; i < 8; ++i)
#pragma unroll
    for (int j = 0; j < 4; ++j) acc[i][j] = f32x4{0.f, 0.f, 0.f, 0.f};

  auto SA = [&](int buf, int kt, int l) {
    const int e  = split * eps + (kt >> 5);
    const int i0 = (kt & 31) << 5;
    const int r  = (l * 4 + wid) * 16 + rsub;
    const int sg = js ^ ((r >> 1) & 3);
    GLOAD_LDS16(xs + ((size_t)e << 22) + ((size_t)(row0 + r) << 10) + i0 + sg * 8,
                &As[buf][(l * 4 + wid) * 512]);
  };
  auto SB = [&](int buf, int kt, int l) {
    const int e  = split * eps + (kt >> 5);
    const int i0 = (kt & 31) << 5;
    const int r  = (l * 4 + wid) * 16 + rsub;
    const int sg = js ^ ((r >> 1) & 3);
    GLOAD_LDS16(wb + ((size_t)e << 20) + ((size_t)(col0 + r) << 10) + i0 + sg * 8,
                &Bs[buf][(l * 4 + wid) * 512]);
  };
  auto STAGE = [&](int buf, int kt) {
#pragma unroll
    for (int l = 0; l < 4; ++l) SA(buf, kt, l);
#pragma unroll
    for (int l = 0; l < 2; ++l) SB(buf, kt, l);
  };

  const int NKT = eps << 5;   // 32 kt per expert (BK=32)

  // prologue: 12 outstanding (tiles 0 and 1)
  STAGE(0, 0);
  STAGE(1, 1);

  int cur = 0;
#pragma unroll 1
  for (int kt = 0; kt < NKT; ++kt) {
    // own 6 loads of tile kt are the oldest of <=12 outstanding
    if (kt == NKT - 1) { WAITV0; } else { WAITV6; }
    BARRIER;           // all waves: tile kt resident; tile kt-1 reads consumed

    // prefetch tile kt+2 into the buffer tile kt-1 used (freed at the barrier)
    if (kt + 2 < NKT) { int s = cur + 2; if (s >= 3) s -= 3; STAGE(s, kt + 2); }

    // interior: compiler-scheduled (counted lgkmcnt between ds_read and MFMA)
    bf16x8 a[8], b[4];
#pragma unroll
    for (int mi = 0; mi < 8; ++mi) {
      const int r = wm * 128 + mi * 16 + frow;
      a[mi] = *(const bf16x8*)&As[cur][r * 32 + (hi ^ ((r >> 1) & 3)) * 8];
    }
#pragma unroll
    for (int ni = 0; ni < 4; ++ni) {
      const int r = wn * 64 + ni * 16 + frow;
      b[ni] = *(const bf16x8*)&Bs[cur][r * 32 + (hi ^ ((r >> 1) & 3)) * 8];
    }
#pragma unroll
    for (int mi = 0; mi < 8; ++mi)
#pragma unroll
      for (int ni = 0; ni < 4; ++ni)
        acc[mi][ni] = __builtin_amdgcn_mfma_f32_16x16x32_bf16(
            a[mi], b[ni], acc[mi][ni], 0, 0, 0);

    if (++cur == 3) cur = 0;
  }

  // split-K contribution via atomics (out pre-zeroed)
  const int orow0 = row0 + wm * 128 + hi * 4;
  const int ocol0 = col0 + wn * 64 + frow;
#pragma unroll
  for (int mi = 0; mi < 8; ++mi)
#pragma unroll
    for (int j = 0; j < 4; ++j) {
      const int r = orow0 + mi * 16 + j;
#pragma unroll
      for (int ni = 0; ni < 4; ++ni)
        atomicAdd(out + (size_t)r * ODIM + ocol0 + ni * 16, acc[mi][ni][j]);
    }
}

extern "C" void kernel_launch(void* const* d_in, const int* in_sizes, int n_in,
                              void* d_out, int out_size, void* d_ws, size_t ws_size,
                              hipStream_t stream) {
  const float* x  = (const float*)d_in[0];   // [4096][1024]
  const float* w  = (const float*)d_in[1];   // [32][1024][1024]
  const float* gw = (const float*)d_in[2];   // [32][1024]
  const float* gb = (const float*)d_in[3];   // [32]
  float* out = (float*)d_out;                // [4096][1024]

  const size_t MiB = 1u << 20;
  int EPR;
  if      (ws_size >= 330 * MiB) EPR = 32;
  else if (ws_size >=  90 * MiB) EPR = 8;
  else                           EPR = 4;
  const int NR = NEXP / EPR;

  u16*   xs   = (u16*)d_ws;                                      // EPR * 8 MiB
  u16*   wbuf = (u16*)((char*)d_ws + (size_t)EPR * 8 * MiB);     // EPR * 2 MiB
  float* gT   = (float*)((char*)d_ws + (size_t)EPR * 10 * MiB);  // 512 KiB
  u16*   xb   = (u16*)((char*)d_ws + (size_t)EPR * 10 * MiB + MiB);  // 8 MiB

  zero_kernel<<<(BSZ * ODIM / 4) / 256, 256, 0, stream>>>(out);
  conv_kernel<<<(BSZ * IDIM / 8) / 256, 256, 0, stream>>>(x, xb);
  gate_kernel<<<BSZ / 4, 256, 0, stream>>>(x, gw, gb, gT);

  for (int r = 0; r < NR; ++r) {
    conv_kernel<<<EPR * 512, 256, 0, stream>>>(w + (size_t)r * EPR * IDIM * ODIM, wbuf);
    scale_kernel<<<EPR * 2048, 256, 0, stream>>>(xb, gT, xs, r * EPR);
    gemm_kernel<<<512, 256, 0, stream>>>(xs, wbuf, out, EPR / 4);
  }
}

// Round 11
// 445.444 us; speedup vs baseline: 1.1911x; 1.0745x over previous
//
#include <hip/hip_runtime.h>
#include <hip/hip_bf16.h>
#include <math.h>

// MOE: out[b,o] = sum_n gelu(x@gw^T+gb)[b,n] * (x @ W_n^T)[b,o]
// R11: exact m201 8-phase port. xs pre-scale -> pure bf16 GEMM
// (M=4096,N=1024,K=32768). 256x256 tile, BK=64, 8 waves (2Mx4N) of 128x64.
// Phases = C-quadrants (Ah x Bh) in order (0,0),(0,1),(1,1),(1,0):
// reads/phase 12/4/8/4; stage stream [(t+1).Bh0, (t+2).Ah0, (t+2).Bh1,
// (t+2).Ah1]; vmcnt(6) at P4 retires exactly through (t+1).Bh0 (3 half-tiles
// in flight, never 0). Every restaged half is proven read-complete by an
// intervening lgkmcnt(0)+barrier. Split-K x4 via fp32 atomics.

#define BSZ  4096
#define NEXP 32
#define IDIM 1024
#define ODIM 1024

typedef unsigned short u16;
typedef __attribute__((ext_vector_type(8))) short bf16x8;
typedef __attribute__((ext_vector_type(4))) float f32x4;

#define GLOAD_LDS16(g, l) __builtin_amdgcn_global_load_lds( \
    (const __attribute__((address_space(1))) void*)(g),     \
    (__attribute__((address_space(3))) void*)(l), 16, 0, 0)

#define WAITL0 asm volatile("s_waitcnt lgkmcnt(0)" ::: "memory")
#define WAITL8 asm volatile("s_waitcnt lgkmcnt(8)" ::: "memory")
#define WAITV4 asm volatile("s_waitcnt vmcnt(4)" ::: "memory")
#define WAITV6 asm volatile("s_waitcnt vmcnt(6)" ::: "memory")
#define WAITV0 asm volatile("s_waitcnt vmcnt(0)" ::: "memory")
#define BAR __builtin_amdgcn_s_barrier()

__device__ __forceinline__ u16 f2bf(float f) {
  unsigned u = __float_as_uint(f);
  return (u16)((u + 0x7FFFu + ((u >> 16) & 1u)) >> 16);  // RNE
}

// ---------------- zero d_out ----------------
__global__ void zero_kernel(float* __restrict__ out) {
  int i = blockIdx.x * blockDim.x + threadIdx.x;
  ((float4*)out)[i] = make_float4(0.f, 0.f, 0.f, 0.f);
}

// ---------------- fp32 -> bf16 conversion (8 elems/thread) ----------------
__global__ void conv_kernel(const float* __restrict__ in, u16* __restrict__ outb) {
  int i = blockIdx.x * blockDim.x + threadIdx.x;
  const float4* p = (const float4*)in + (size_t)i * 2;
  float4 a = p[0], b = p[1];
  union { bf16x8 v; u16 s[8]; } o;
  o.s[0] = f2bf(a.x); o.s[1] = f2bf(a.y); o.s[2] = f2bf(a.z); o.s[3] = f2bf(a.w);
  o.s[4] = f2bf(b.x); o.s[5] = f2bf(b.y); o.s[6] = f2bf(b.z); o.s[7] = f2bf(b.w);
  ((bf16x8*)outb)[i] = o.v;
}

// ---------------- gate: gT[n][b] = gelu(x[b]·gw[n] + gb[n]) ----------------
__global__ void gate_kernel(const float* __restrict__ x, const float* __restrict__ gw,
                            const float* __restrict__ gb, float* __restrict__ gT) {
  const int lane = threadIdx.x & 63;
  const int row = blockIdx.x * 4 + (threadIdx.x >> 6);
  const float4* xr = (const float4*)(x + (size_t)row * IDIM);
  float4 xv[4];
#pragma unroll
  for (int t = 0; t < 4; ++t) xv[t] = xr[t * 64 + lane];
  for (int n = 0; n < NEXP; ++n) {
    const float4* wr = (const float4*)(gw + (size_t)n * IDIM);
    float s = 0.f;
#pragma unroll
    for (int t = 0; t < 4; ++t) {
      float4 wv = wr[t * 64 + lane];
      s += xv[t].x * wv.x + xv[t].y * wv.y + xv[t].z * wv.z + xv[t].w * wv.w;
    }
#pragma unroll
    for (int off = 32; off > 0; off >>= 1) s += __shfl_down(s, off, 64);
    if (lane == 0) {
      float v = s + gb[n];
      gT[(size_t)n * BSZ + row] = 0.5f * v * (1.0f + erff(v * 0.70710678118f));
    }
  }
}

// ---------------- xs[e][b][i] = bf16(g[b, base+e] * xb[b][i]) ----------------
__global__ void scale_kernel(const u16* __restrict__ xb, const float* __restrict__ gT,
                             u16* __restrict__ xs, int base) {
  int idx = blockIdx.x * 256 + threadIdx.x;
  int chunk = idx & 127;
  int b = (idx >> 7) & 4095;
  int e = idx >> 19;
  union { bf16x8 v; u16 s[8]; } iv, o;
  iv.v = *(const bf16x8*)&xb[((size_t)b << 10) + chunk * 8];
  float g = gT[((size_t)(base + e) << 12) + b];
#pragma unroll
  for (int j = 0; j < 8; ++j) {
    float f = __uint_as_float((unsigned)iv.s[j] << 16);
    o.s[j] = f2bf(g * f);
  }
  *(bf16x8*)&xs[((size_t)e << 22) + ((size_t)b << 10) + chunk * 8] = o.v;
}

// ---------------- main GEMM (m201 8-phase) ----------------
// 256 blocks (1/CU), 512 threads (8 waves 2Mx4N, wave = 128x64 output).
// K per block = eps experts * 1024; NKT = eps*16 K-tiles of BK=64.
__global__ __launch_bounds__(512, 2) void gemm_kernel(
    const u16* __restrict__ xs,   // [EPR][4096][1024] bf16 (pre-scaled)
    const u16* __restrict__ wb,   // [EPR][1024][1024] bf16 (e,o,i)
    float* __restrict__ out,      // [4096][1024] fp32
    int eps)                      // experts per split (EPR/4)
{
  __shared__ u16 As[2][256 * 64];   // 64 KB
  __shared__ u16 Bs[2][256 * 64];   // 64 KB (128 KiB total)

  const int tid  = threadIdx.x;
  const int lane = tid & 63;
  const int wid  = tid >> 6;     // 0..7
  const int wm   = wid >> 2;     // 0..1 (M)
  const int wn   = wid & 3;      // 0..3 (N)

  // XCD-chunked block swizzle (256 % 8 == 0 -> bijective)
  const int orig  = blockIdx.x;
  const int wgid  = (orig & 7) * 32 + (orig >> 3);
  const int mtile = wgid & 15;
  const int grp   = wgid >> 4;          // 0..15 = (ntile, split)
  const int split = grp & 3;
  const int col0  = (grp >> 2) * 256;
  const int row0  = mtile * 256;

  const int jsrc = (lane & 7) ^ (lane >> 3);  // pre-swizzled source granule
  const int frow = lane & 15;
  const int hi   = lane >> 4;
  const int fs   = frow & 7;

  // acc[Ah][Bh][mi][ni] — all literal-indexed
  f32x4 acc[2][2][4][2];
#pragma unroll
  for (int p = 0; p < 2; ++p)
#pragma unroll
    for (int q = 0; q < 2; ++q)
#pragma unroll
      for (int mi = 0; mi < 4; ++mi)
#pragma unroll
        for (int ni = 0; ni < 2; ++ni) acc[p][q][mi][ni] = f32x4{0.f, 0.f, 0.f, 0.f};

  // stage half h (rows h*128..+128) of A or B for K-tile kt into buf (2 gloads)
  auto SA = [&](int buf, int kt, int h) {
    const int e = split * eps + (kt >> 4);
    const size_t base = ((size_t)e << 22) + ((size_t)row0 << 10) + ((kt & 15) << 6) + jsrc * 8;
#pragma unroll
    for (int c = 0; c < 2; ++c) {
      const int r = h * 128 + c * 64 + wid * 8 + (lane >> 3);
      GLOAD_LDS16(xs + base + ((size_t)r << 10), &As[buf][(h * 128 + c * 64 + wid * 8) * 64]);
    }
  };
  auto SB = [&](int buf, int kt, int h) {
    const int e = split * eps + (kt >> 4);
    const size_t base = ((size_t)e << 20) + ((size_t)col0 << 10) + ((kt & 15) << 6) + jsrc * 8;
#pragma unroll
    for (int c = 0; c < 2; ++c) {
      const int r = h * 128 + c * 64 + wid * 8 + (lane >> 3);
      GLOAD_LDS16(wb + base + ((size_t)r << 10), &Bs[buf][(h * 128 + c * 64 + wid * 8) * 64]);
    }
  };

  const int NKT = eps << 4;

  // ---- prologue: t0 fully (vmcnt 4 pacing), then t1.{Ah0,Bh1,Ah1} (vmcnt 6) ----
  SA(0, 0, 0); SB(0, 0, 0); SA(0, 0, 1); SB(0, 0, 1);
  WAITV4;
  if (NKT > 1) { SA(1, 1, 0); SB(1, 1, 1); SA(1, 1, 1); WAITV6; } else { WAITV0; }
  BAR;

#pragma unroll 1
  for (int kt = 0; kt < NKT; ++kt) {
    const int buf = kt & 1;
    const u16* A_ = &As[buf][0];
    const u16* B_ = &Bs[buf][0];
    bf16x8 a[4][2], b0[2][2], b1[2][2];

    // ======== P1: quadrant (Ah0, Bh0) — 12 reads; stage (kt+1).Bh0 ========
#pragma unroll
    for (int mi = 0; mi < 4; ++mi)
#pragma unroll
      for (int kk = 0; kk < 2; ++kk)
        a[mi][kk] = *(const bf16x8*)&A_[(wm * 64 + mi * 16 + frow) * 64 + (((kk << 2) + hi) ^ fs) * 8];
#pragma unroll
    for (int ni = 0; ni < 2; ++ni)
#pragma unroll
      for (int kk = 0; kk < 2; ++kk)
        b0[ni][kk] = *(const bf16x8*)&B_[(wn * 32 + ni * 16 + frow) * 64 + (((kk << 2) + hi) ^ fs) * 8];
    if (kt + 1 < NKT) SB(buf ^ 1, kt + 1, 0);
    WAITL8;
    BAR;
    WAITL0;
    __builtin_amdgcn_s_setprio(1);
#pragma unroll
    for (int mi = 0; mi < 4; ++mi)
#pragma unroll
      for (int ni = 0; ni < 2; ++ni)
#pragma unroll
        for (int kk = 0; kk < 2; ++kk)
          acc[0][0][mi][ni] = __builtin_amdgcn_mfma_f32_16x16x32_bf16(
              a[mi][kk], b0[ni][kk], acc[0][0][mi][ni], 0, 0, 0);
    __builtin_amdgcn_s_setprio(0);
    BAR;

    // ======== P2: quadrant (Ah0, Bh1) — 4 reads; stage (kt+2).Ah0 ========
#pragma unroll
    for (int ni = 0; ni < 2; ++ni)
#pragma unroll
      for (int kk = 0; kk < 2; ++kk)
        b1[ni][kk] = *(const bf16x8*)&B_[(128 + wn * 32 + ni * 16 + frow) * 64 + (((kk << 2) + hi) ^ fs) * 8];
    if (kt + 2 < NKT) SA(buf, kt + 2, 0);
    BAR;
    WAITL0;
    __builtin_amdgcn_s_setprio(1);
#pragma unroll
    for (int mi = 0; mi < 4; ++mi)
#pragma unroll
      for (int ni = 0; ni < 2; ++ni)
#pragma unroll
        for (int kk = 0; kk < 2; ++kk)
          acc[0][1][mi][ni] = __builtin_amdgcn_mfma_f32_16x16x32_bf16(
              a[mi][kk], b1[ni][kk], acc[0][1][mi][ni], 0, 0, 0);
    __builtin_amdgcn_s_setprio(0);
    BAR;

    // ======== P3: quadrant (Ah1, Bh1) — 8 reads; stage (kt+2).Bh1 ========
#pragma unroll
    for (int mi = 0; mi < 4; ++mi)
#pragma unroll
      for (int kk = 0; kk < 2; ++kk)
        a[mi][kk] = *(const bf16x8*)&A_[(128 + wm * 64 + mi * 16 + frow) * 64 + (((kk << 2) + hi) ^ fs) * 8];
    if (kt + 2 < NKT) SB(buf, kt + 2, 1);
    BAR;
    WAITL0;
    __builtin_amdgcn_s_setprio(1);
#pragma unroll
    for (int mi = 0; mi < 4; ++mi)
#pragma unroll
      for (int ni = 0; ni < 2; ++ni)
#pragma unroll
        for (int kk = 0; kk < 2; ++kk)
          acc[1][1][mi][ni] = __builtin_amdgcn_mfma_f32_16x16x32_bf16(
              a[mi][kk], b1[ni][kk], acc[1][1][mi][ni], 0, 0, 0);
    __builtin_amdgcn_s_setprio(0);
    BAR;

    // ======== P4: quadrant (Ah1, Bh0) — 4 reads; stage (kt+2).Ah1; vmcnt ========
#pragma unroll
    for (int ni = 0; ni < 2; ++ni)
#pragma unroll
      for (int kk = 0; kk < 2; ++kk)
        b0[ni][kk] = *(const bf16x8*)&B_[(wn * 32 + ni * 16 + frow) * 64 + (((kk << 2) + hi) ^ fs) * 8];
    if (kt + 2 < NKT) SA(buf, kt + 2, 1);
    BAR;
    WAITL0;
    __builtin_amdgcn_s_setprio(1);
#pragma unroll
    for (int mi = 0; mi < 4; ++mi)
#pragma unroll
      for (int ni = 0; ni < 2; ++ni)
#pragma unroll
        for (int kk = 0; kk < 2; ++kk)
          acc[1][0][mi][ni] = __builtin_amdgcn_mfma_f32_16x16x32_bf16(
              a[mi][kk], b0[ni][kk], acc[1][0][mi][ni], 0, 0, 0);
    __builtin_amdgcn_s_setprio(0);
    if (kt + 1 < NKT) {
      if (kt + 2 < NKT) { WAITV6; } else { WAITV0; }   // retire through (kt+1).Bh0
    }
    BAR;
  }

  // ---- epilogue: split-K contribution via atomics (out pre-zeroed) ----
#pragma unroll
  for (int Ah = 0; Ah < 2; ++Ah)
#pragma unroll
    for (int Bh = 0; Bh < 2; ++Bh)
#pragma unroll
      for (int mi = 0; mi < 4; ++mi)
#pragma unroll
        for (int j = 0; j < 4; ++j) {
          const int r = row0 + Ah * 128 + wm * 64 + mi * 16 + hi * 4 + j;
#pragma unroll
          for (int ni = 0; ni < 2; ++ni)
            atomicAdd(out + (size_t)r * ODIM + col0 + Bh * 128 + wn * 32 + ni * 16 + frow,
                      acc[Ah][Bh][mi][ni][j]);
        }
}

extern "C" void kernel_launch(void* const* d_in, const int* in_sizes, int n_in,
                              void* d_out, int out_size, void* d_ws, size_t ws_size,
                              hipStream_t stream) {
  const float* x  = (const float*)d_in[0];   // [4096][1024]
  const float* w  = (const float*)d_in[1];   // [32][1024][1024]
  const float* gw = (const float*)d_in[2];   // [32][1024]
  const float* gb = (const float*)d_in[3];   // [32]
  float* out = (float*)d_out;                // [4096][1024]

  const size_t MiB = 1u << 20;
  int EPR;
  if      (ws_size >= 330 * MiB) EPR = 32;
  else if (ws_size >=  90 * MiB) EPR = 8;
  else                           EPR = 4;
  const int NR = NEXP / EPR;

  u16*   xs   = (u16*)d_ws;                                      // EPR * 8 MiB
  u16*   wbuf = (u16*)((char*)d_ws + (size_t)EPR * 8 * MiB);     // EPR * 2 MiB
  float* gT   = (float*)((char*)d_ws + (size_t)EPR * 10 * MiB);  // 512 KiB
  u16*   xb   = (u16*)((char*)d_ws + (size_t)EPR * 10 * MiB + MiB);  // 8 MiB

  zero_kernel<<<(BSZ * ODIM / 4) / 256, 256, 0, stream>>>(out);
  conv_kernel<<<(BSZ * IDIM / 8) / 256, 256, 0, stream>>>(x, xb);
  gate_kernel<<<BSZ / 4, 256, 0, stream>>>(x, gw, gb, gT);

  for (int r = 0; r < NR; ++r) {
    conv_kernel<<<EPR * 512, 256, 0, stream>>>(w + (size_t)r * EPR * IDIM * ODIM, wbuf);
    scale_kernel<<<EPR * 2048, 256, 0, stream>>>(xb, gT, xs, r * EPR);
    gemm_kernel<<<256, 512, 0, stream>>>(xs, wbuf, out, EPR / 4);
  }
}